// Round 8
// baseline (182.492 us; speedup 1.0000x reference)
//
#include <hip/hip_runtime.h>

// GaussianRegLoss — R8: MEASUREMENT ROUND.
// Same kernel as R7 (VPT=2, 2048 blocks, launch_bounds(256,8), nontemporal
// ext-vector loads) but the j-loop runs `reps`=4 times (runtime arg), with an
// asm pointer-laundering barrier per pass so loads can't be CSE'd/hoisted.
// acc is scaled by inv_reps = 0.25f (exact power of two -> no extra rounding
// beyond the 4x-summation order). Purpose: main's duration ~4x (~60-80 us)
// pushes it into rocprof's top-5 so we finally see its hbm_gbps / FETCH_SIZE /
// VALUBusy / Occupancy and can decide roofline-vs-headroom on evidence.
//   mean over [bs,nj,h,w,d] of (exp(-||grid-kpt||^2)/(2*sigma^2) - sigmoid(hm))^2

#define HWD   262144          // 64*64*64
#define NJ    23
#define BS    4
#define NTOT  24117248.0      // BS*NJ*HWD
#define BLK   256
#define VPT   2               // voxels per thread
#define BLOCKS_PER_B 512      // HWD / (BLK*VPT)
#define NBLOCKS (BS * BLOCKS_PER_B)   // 2048

typedef float f32x2 __attribute__((ext_vector_type(2)));
typedef float f32x4 __attribute__((ext_vector_type(4)));

__global__ __launch_bounds__(BLK, 8) void gauss_loss_main(
    const float* __restrict__ kpts_pred,   // [BS,3,NJ]
    const float* __restrict__ heatmaps,    // [BS,NJ,HWD]
    const float* __restrict__ grids,       // [BS,HWD,3]
    float* __restrict__ partials,          // [NBLOCKS]
    int reps, float inv_reps)
{
    // b from blockIdx only -> wave-uniform -> kpts via scalar (SGPR) loads.
    const int b  = blockIdx.x >> 9;                       // 512 blocks per batch
    const int x2 = ((blockIdx.x & 511) * BLK + threadIdx.x) * VPT;

    // grids for 2 voxels: 6 contiguous floats (24B, 8B-aligned)
    const float* gp = grids + ((size_t)b * HWD + x2) * 3;
    const f32x2 ga = __builtin_nontemporal_load(reinterpret_cast<const f32x2*>(gp));
    const f32x2 gb = __builtin_nontemporal_load(reinterpret_cast<const f32x2*>(gp + 2));
    const f32x2 gc = __builtin_nontemporal_load(reinterpret_cast<const f32x2*>(gp + 4));
    const float gx[VPT] = {ga.x, gb.y};
    const float gy[VPT] = {ga.y, gc.x};
    const float gz[VPT] = {gb.x, gc.y};

    const float* kp = kpts_pred + b * 3 * NJ;             // uniform base

    const float LOG2E = 1.4426950408889634f;
    float acc = 0.f;

    // Register double-buffer over joints, chunks 6/6/6/5 (12 f32x2 = 24 VGPR).
    f32x2 ha[6], hb[6];

#define LD(buf, base, n)                                                     \
    _Pragma("unroll")                                                        \
    for (int q = 0; q < (n); ++q)                                            \
        buf[q] = __builtin_nontemporal_load(                                 \
            reinterpret_cast<const f32x2*>(hmp + (size_t)((base) + q) * HWD));

#define CP(buf, base, n)                                                     \
    _Pragma("unroll")                                                        \
    for (int q = 0; q < (n); ++q) {                                          \
        const int j = (base) + q;                                            \
        const float cx = kp[j], cy = kp[NJ + j], cz = kp[2 * NJ + j];        \
        const float hv[VPT] = {buf[q].x, buf[q].y};                          \
        _Pragma("unroll")                                                    \
        for (int i = 0; i < VPT; ++i) {                                      \
            const float dx = gx[i] - cx, dy = gy[i] - cy, dz = gz[i] - cz;   \
            const float sq = dx * dx + dy * dy + dz * dz;                    \
            const float gauss = __builtin_amdgcn_exp2f(-sq * LOG2E) * 0.02f; \
            const float e     = __builtin_amdgcn_exp2f(-hv[i] * LOG2E);      \
            const float sig   = __builtin_amdgcn_rcpf(1.0f + e);             \
            const float dd    = gauss - sig;                                 \
            acc += dd * dd;                                                  \
        }                                                                    \
    }

    const float* hmp0 = heatmaps + (size_t)b * NJ * HWD + x2;
    for (int r = 0; r < reps; ++r) {
        const float* hmp = hmp0;
        // launder the pointer: compiler cannot prove pass r's loads duplicate
        // pass r-1's -> loads are re-issued every pass (real HBM traffic x reps)
        asm volatile("" : "+v"(hmp));
        LD(ha, 0, 6); LD(hb, 6, 6);
        CP(ha, 0, 6); LD(ha, 12, 6);
        CP(hb, 6, 6); LD(hb, 18, 5);
        CP(ha, 12, 6);
        CP(hb, 18, 5);
    }
#undef LD
#undef CP

    acc *= inv_reps;   // 0.25f: exact (power of two)

    // wave (64) reduce, then cross-wave via LDS
    #pragma unroll
    for (int off = 32; off > 0; off >>= 1)
        acc += __shfl_down(acc, off, 64);
    __shared__ float s_w[BLK / 64];
    const int lane = threadIdx.x & 63, wid = threadIdx.x >> 6;
    if (lane == 0) s_w[wid] = acc;
    __syncthreads();
    if (threadIdx.x == 0)
        partials[blockIdx.x] = (s_w[0] + s_w[1]) + (s_w[2] + s_w[3]);
}

__global__ __launch_bounds__(BLK) void gauss_loss_reduce(
    const float* __restrict__ partials, float* __restrict__ out)
{
    // 2048 partials: 256 threads x 2 f32x4
    const f32x4 v0 = reinterpret_cast<const f32x4*>(partials)[threadIdx.x];
    const f32x4 v1 = reinterpret_cast<const f32x4*>(partials)[threadIdx.x + BLK];
    double acc = (((double)v0.x + (double)v0.y) + ((double)v0.z + (double)v0.w))
               + (((double)v1.x + (double)v1.y) + ((double)v1.z + (double)v1.w));
    #pragma unroll
    for (int off = 32; off > 0; off >>= 1)
        acc += __shfl_down(acc, off, 64);
    __shared__ double s_w[BLK / 64];
    const int lane = threadIdx.x & 63, wid = threadIdx.x >> 6;
    if (lane == 0) s_w[wid] = acc;
    __syncthreads();
    if (threadIdx.x == 0)
        out[0] = (float)(((s_w[0] + s_w[1]) + (s_w[2] + s_w[3])) / NTOT);
}

extern "C" void kernel_launch(void* const* d_in, const int* in_sizes, int n_in,
                              void* d_out, int out_size, void* d_ws, size_t ws_size,
                              hipStream_t stream) {
    // input order: 0=kpts_gt (unused), 1=kpts_pred, 2=heatmaps, 3=grids
    const float* kpts_pred = (const float*)d_in[1];
    const float* heatmaps  = (const float*)d_in[2];
    const float* grids     = (const float*)d_in[3];
    float* out      = (float*)d_out;
    float* partials = (float*)d_ws;   // NBLOCKS floats, fully overwritten each call

    // reps=4 diagnostic: main runs the full stream 4x so it surfaces in
    // rocprof's top-5 with its own hbm_gbps. Revert to reps=1 next round.
    gauss_loss_main<<<NBLOCKS, BLK, 0, stream>>>(kpts_pred, heatmaps, grids,
                                                 partials, 4, 0.25f);
    gauss_loss_reduce<<<1, BLK, 0, stream>>>(partials, out);
}

// Round 9
// 171.522 us; speedup vs baseline: 1.0640x; 1.0640x over previous
//
#include <hip/hip_runtime.h>

// GaussianRegLoss — R9: contiguous-stream restructure (DRAM row locality).
//   mean over [bs,nj,h,w,d] of (exp(-||grid-kpt||^2)/(2*sigma^2) - sigmoid(hm))^2
// R8 measurement: main(reps=1) ~27us @ ~4.0 TB/s vs 17.3us floor; L3-resident
// passes run 11.6us -> not compute/occupancy bound. Theory: 23 heatmap streams
// per wave at 1MB stride thrash DRAM row buffers. This version: one block per
// (b,j,chunk) so heatmap reads are LINEAR 64KB streams (fill-kernel pattern,
// 6.8 TB/s). Grids re-read 23x but L2-resident: chunk ≡ blockIdx (mod 8) pins
// all 23 same-chunk blocks to one XCD (round-robin heuristic) -> 1.5MB/XCD
// grid footprint < 4MB L2. kpts: 3 block-uniform SGPR scalars. reps reverted.

#define HWD    262144         // 64*64*64
#define NJ     23
#define BS     4
#define NTOT   24117248.0     // BS*NJ*HWD
#define BLK    256
#define NCHUNK 16             // voxel chunks per (b,j)
#define CVOX   16384          // HWD / NCHUNK voxels per block
#define NPAIR  (BS * NJ)      // 92
#define NBLOCKS (NPAIR * NCHUNK)  // 1472
#define ITERS  16             // CVOX / (BLK*4): float4 iters per thread

typedef float f32x4 __attribute__((ext_vector_type(4)));

__global__ __launch_bounds__(BLK, 6) void gauss_loss_main(
    const float* __restrict__ kpts_pred,   // [BS,3,NJ]
    const float* __restrict__ heatmaps,    // [BS,NJ,HWD]
    const float* __restrict__ grids,       // [BS,HWD,3]
    float* __restrict__ partials)          // [NBLOCKS]
{
    const int g     = blockIdx.x;
    const int pc    = g >> 3;                       // [0,184)
    const int pair  = pc % NPAIR;                   // (b,j)
    const int chunk = (g & 7) | ((pc / NPAIR) << 3);  // chunk ≡ g (mod 8)
    const int b     = pair / NJ;
    const int j     = pair % NJ;

    // block-uniform keypoint -> SGPRs
    const float cx = kpts_pred[b * 3 * NJ + j];
    const float cy = kpts_pred[b * 3 * NJ + NJ + j];
    const float cz = kpts_pred[b * 3 * NJ + 2 * NJ + j];

    // linear streams: hm 64KB contiguous per block; grids 192KB contiguous
    const float* hmp = heatmaps + ((size_t)(b * NJ + j)) * HWD
                                + (size_t)chunk * CVOX + (size_t)threadIdx.x * 4;
    const float* gp  = grids + (size_t)b * HWD * 3
                             + (size_t)chunk * (CVOX * 3) + (size_t)threadIdx.x * 12;

    const float LOG2E = 1.4426950408889634f;
    float acc = 0.f;

    f32x4 hA, aA0, aA1, aA2, hB, aB0, aB1, aB2;

    // per iter: wave reads 1KB hm (NT, zero reuse) + 3KB grids (cached, 23x reuse)
#define LOAD(H, G0, G1, G2, it)                                               \
    {                                                                         \
        const float* hp_ = hmp + (it) * (BLK * 4);                            \
        const float* gp_ = gp + (it) * (BLK * 12);                            \
        H  = __builtin_nontemporal_load(reinterpret_cast<const f32x4*>(hp_)); \
        G0 = *reinterpret_cast<const f32x4*>(gp_);                            \
        G1 = *reinterpret_cast<const f32x4*>(gp_ + 4);                        \
        G2 = *reinterpret_cast<const f32x4*>(gp_ + 8);                        \
    }

#define COMP(H, G0, G1, G2)                                                   \
    {                                                                         \
        const float gxv[4] = {G0.x, G0.w, G1.z, G2.y};                        \
        const float gyv[4] = {G0.y, G1.x, G1.w, G2.z};                        \
        const float gzv[4] = {G0.z, G1.y, G2.x, G2.w};                        \
        const float hv[4]  = {H.x, H.y, H.z, H.w};                            \
        _Pragma("unroll")                                                     \
        for (int i = 0; i < 4; ++i) {                                         \
            const float dx = gxv[i] - cx, dy = gyv[i] - cy, dz = gzv[i] - cz; \
            const float sq = dx * dx + dy * dy + dz * dz;                     \
            const float gauss = __builtin_amdgcn_exp2f(-sq * LOG2E) * 0.02f;  \
            const float e     = __builtin_amdgcn_exp2f(-hv[i] * LOG2E);       \
            const float sig   = __builtin_amdgcn_rcpf(1.0f + e);              \
            const float dd    = gauss - sig;                                  \
            acc += dd * dd;                                                   \
        }                                                                     \
    }

    // 2-deep software pipeline over 16 iters
    LOAD(hA, aA0, aA1, aA2, 0)
    #pragma unroll
    for (int it = 0; it < ITERS; it += 2) {
        LOAD(hB, aB0, aB1, aB2, it + 1)
        COMP(hA, aA0, aA1, aA2)
        if (it + 2 < ITERS) LOAD(hA, aA0, aA1, aA2, it + 2)
        COMP(hB, aB0, aB1, aB2)
    }
#undef LOAD
#undef COMP

    // wave (64) reduce, then cross-wave via LDS
    #pragma unroll
    for (int off = 32; off > 0; off >>= 1)
        acc += __shfl_down(acc, off, 64);
    __shared__ float s_w[BLK / 64];
    const int lane = threadIdx.x & 63, wid = threadIdx.x >> 6;
    if (lane == 0) s_w[wid] = acc;
    __syncthreads();
    if (threadIdx.x == 0)
        partials[blockIdx.x] = (s_w[0] + s_w[1]) + (s_w[2] + s_w[3]);
}

__global__ __launch_bounds__(BLK) void gauss_loss_reduce(
    const float* __restrict__ partials, float* __restrict__ out, int n)
{
    double acc = 0.0;
    for (int i = threadIdx.x; i < n; i += BLK) acc += (double)partials[i];
    #pragma unroll
    for (int off = 32; off > 0; off >>= 1)
        acc += __shfl_down(acc, off, 64);
    __shared__ double s_w[BLK / 64];
    const int lane = threadIdx.x & 63, wid = threadIdx.x >> 6;
    if (lane == 0) s_w[wid] = acc;
    __syncthreads();
    if (threadIdx.x == 0)
        out[0] = (float)(((s_w[0] + s_w[1]) + (s_w[2] + s_w[3])) / NTOT);
}

extern "C" void kernel_launch(void* const* d_in, const int* in_sizes, int n_in,
                              void* d_out, int out_size, void* d_ws, size_t ws_size,
                              hipStream_t stream) {
    // input order: 0=kpts_gt (unused), 1=kpts_pred, 2=heatmaps, 3=grids
    const float* kpts_pred = (const float*)d_in[1];
    const float* heatmaps  = (const float*)d_in[2];
    const float* grids     = (const float*)d_in[3];
    float* out      = (float*)d_out;
    float* partials = (float*)d_ws;   // NBLOCKS floats, fully overwritten each call

    gauss_loss_main<<<NBLOCKS, BLK, 0, stream>>>(kpts_pred, heatmaps, grids, partials);
    gauss_loss_reduce<<<1, BLK, 0, stream>>>(partials, out, NBLOCKS);
}